// Round 11
// baseline (2578.979 us; speedup 1.0000x reference)
//
#include <hip/hip_runtime.h>
#include <cstdint>

typedef unsigned short u16;
typedef unsigned int u32;
typedef __bf16 bf16_t;
typedef bf16_t bf16x8 __attribute__((ext_vector_type(8)));
typedef float f32x4 __attribute__((ext_vector_type(4)));

#define DMODEL 4096
#define DFF 11008
#define MROWS 8192

__device__ __forceinline__ u16 f2bf(float f) {
  u32 u = __builtin_bit_cast(u32, f);
  u += 0x7FFFu + ((u >> 16) & 1u);   // RNE
  return (u16)(u >> 16);
}
__device__ __forceinline__ float bf2f(u16 h) {
  return __builtin_bit_cast(float, (u32)h << 16);
}

// async global->LDS, 16B per lane, wave-uniform LDS base + lane*16
#define GLD16(gptr, lptr)                                                  \
  __builtin_amdgcn_global_load_lds(                                        \
      (const __attribute__((address_space(1))) u32*)(gptr),                \
      (__attribute__((address_space(3))) u32*)(lptr), 16, 0, 0)

// ---------------- x -> bf16 ----------------
__global__ void k_cvt_x(const float* __restrict__ x, u16* __restrict__ xb) {
  size_t i = (size_t)blockIdx.x * blockDim.x + threadIdx.x;
  float4 v = reinterpret_cast<const float4*>(x)[i];
  ushort4 o;
  o.x = f2bf(v.x); o.y = f2bf(v.y); o.z = f2bf(v.z); o.w = f2bf(v.w);
  reinterpret_cast<ushort4*>(xb)[i] = o;
}

// ------- dequant (q - z) * s, write TRANSPOSED wT[N][K] as bf16 -------
__global__ void k_dequant_T(const int* __restrict__ q, const int* __restrict__ z,
                            const float* __restrict__ s, u16* __restrict__ wT,
                            int K, int N) {
  __shared__ u16 tile[32][36];
  const int t = threadIdx.x;
  const int n0 = blockIdx.x << 5, k0 = blockIdx.y << 5;
  {
    const int kr = t >> 3, n4 = (t & 7) << 2;
    const int k = k0 + kr, g = k >> 7;
    const int4 qv = *reinterpret_cast<const int4*>(&q[(size_t)k * N + n0 + n4]);
    const int4 zv = *reinterpret_cast<const int4*>(&z[(size_t)g * N + n0 + n4]);
    const float4 sv = *reinterpret_cast<const float4*>(&s[(size_t)g * N + n0 + n4]);
    ushort4 o;
    o.x = f2bf((float)(qv.x - zv.x) * sv.x);
    o.y = f2bf((float)(qv.y - zv.y) * sv.y);
    o.z = f2bf((float)(qv.z - zv.z) * sv.z);
    o.w = f2bf((float)(qv.w - zv.w) * sv.w);
    *reinterpret_cast<ushort4*>(&tile[kr][n4]) = o;
  }
  __syncthreads();
  {
    const int n = t >> 3, ks = (t & 7) << 2;
    ushort4 o;
    o.x = tile[ks + 0][n];
    o.y = tile[ks + 1][n];
    o.z = tile[ks + 2][n];
    o.w = tile[ks + 3][n];
    *reinterpret_cast<ushort4*>(&wT[(size_t)(n0 + n) * K + k0 + ks]) = o;
  }
}

#define BAR asm volatile("s_barrier" ::: "memory")
#define VM4 asm volatile("s_waitcnt vmcnt(4)" ::: "memory")

// ======== fused gate+up: h = silu(x@Wg) * (x@Wu), bf16 out ========
// R6 data schedule (proven). CHANGE vs R6: next-phase fragment ds_reads
// issued at the TOP of the MFMA cluster, NO sched_barrier pin — the reads
// have no dependency on the current (old-set) MFMAs, so the compiler's
// counted lgkmcnt lets all 32 MFMAs issue while the LDS pipe drains.
__global__ __launch_bounds__(512, 2) void k_fused(
    const u16* __restrict__ A, const u16* __restrict__ BgT,
    const u16* __restrict__ BuT, u16* __restrict__ H) {
  constexpr int Kdim = DMODEL;
  __shared__ u16 As[2][2][256 * 32];   // 64KB
  __shared__ u16 Bgs[2][2][128 * 32];  // 32KB
  __shared__ u16 Bus[2][2][128 * 32];  // 32KB

  const int midx = blockIdx.x & 31;   // m-major
  const int nidx = blockIdx.x >> 5;
  const int m0 = midx << 8;
  const int n0 = nidx << 7;
  const int t = threadIdx.x;
  const int lane = t & 63;
  const int wid = t >> 6;
  const int wr = wid >> 2, wc = wid & 3;
  const int r16 = lane & 15, quad = lane >> 4;

  const int lrow4 = lane >> 2;
  const int sslot = ((lane & 3) ^ ((lane >> 3) & 3)) << 3;  // u16 units
  const u16* Asrc = A + (size_t)(m0 + wid * 16 + lrow4) * Kdim + sslot;
  const u16* Gsrc = BgT + (size_t)(n0 + wid * 16 + lrow4) * Kdim + sslot;
  const u16* Usrc = BuT + (size_t)(n0 + wid * 16 + lrow4) * Kdim + sslot;
  const size_t rstep = (size_t)128 * Kdim;
  const int lb = wid * 512;
  constexpr int ntiles = Kdim >> 6;  // 64

#define SAF(tt, kh, bf) do {                                               \
    size_t ko = ((size_t)((tt) & (ntiles - 1)) << 6) + ((kh) << 5);        \
    GLD16(Asrc + ko,         &As[bf][kh][lb]);                             \
    GLD16(Asrc + ko + rstep, &As[bf][kh][lb + 4096]);                      \
  } while (0)
#define SGU(tt, kh, bf) do {                                               \
    size_t ko = ((size_t)((tt) & (ntiles - 1)) << 6) + ((kh) << 5);        \
    GLD16(Gsrc + ko, &Bgs[bf][kh][lb]);                                    \
    GLD16(Usrc + ko, &Bus[bf][kh][lb]);                                    \
  } while (0)

  const int fragoff = (quad ^ ((r16 >> 1) & 3)) << 3;
  const int abase = (wr * 128 + r16) * 32 + fragoff;
  const int bbase = (wc * 32 + r16) * 32 + fragoff;

  f32x4 accg[8][2], accu[8][2];
  const f32x4 zf = {0.f, 0.f, 0.f, 0.f};
#pragma unroll
  for (int mf = 0; mf < 8; ++mf)
#pragma unroll
    for (int nf = 0; nf < 2; ++nf) { accg[mf][nf] = zf; accu[mf][nf] = zf; }

  // two static fragment sets (rule #20: no runtime indexing)
  bf16x8 avA[4], av2A[4], bgA[2], buA[2];
  bf16x8 avB[4], av2B[4], bgB[2], buB[2];

#define PFF(av_, av2_, bg_, bu_, bf, kk) do {                              \
    _Pragma("unroll") for (int ii = 0; ii < 4; ++ii) {                     \
      av_[ii] = *reinterpret_cast<const bf16x8*>(                          \
          &As[bf][kk][abase + ii * 512]);                                  \
      av2_[ii] = *reinterpret_cast<const bf16x8*>(                         \
          &As[bf][kk][abase + 2048 + ii * 512]);                           \
    }                                                                      \
    _Pragma("unroll") for (int nn = 0; nn < 2; ++nn) {                     \
      bg_[nn] = *reinterpret_cast<const bf16x8*>(                          \
          &Bgs[bf][kk][bbase + nn * 512]);                                 \
      bu_[nn] = *reinterpret_cast<const bf16x8*>(                          \
          &Bus[bf][kk][bbase + nn * 512]);                                 \
    }                                                                      \
  } while (0)

  // PH: prefetch next set at cluster TOP (no pin), then 32 MFMA on old set.
#define PHF(av_, av2_, bg_, bu_, nav_, nav2_, nbg_, nbu_, STG, VMW, bfn, kkn) \
  do {                                                                     \
    STG;                                                                   \
    VMW;                                                                   \
    BAR;                                                                   \
    PFF(nav_, nav2_, nbg_, nbu_, bfn, kkn);                                \
    __builtin_amdgcn_s_setprio(1);                                         \
    _Pragma("unroll") for (int ii = 0; ii < 4; ++ii)                       \
      _Pragma("unroll") for (int nn = 0; nn < 2; ++nn) {                   \
        accg[ii][nn] = __builtin_amdgcn_mfma_f32_16x16x32_bf16(            \
            av_[ii], bg_[nn], accg[ii][nn], 0, 0, 0);                      \
        accu[ii][nn] = __builtin_amdgcn_mfma_f32_16x16x32_bf16(            \
            av_[ii], bu_[nn], accu[ii][nn], 0, 0, 0);                      \
      }                                                                    \
    _Pragma("unroll") for (int ii = 0; ii < 4; ++ii)                       \
      _Pragma("unroll") for (int nn = 0; nn < 2; ++nn) {                   \
        accg[4 + ii][nn] = __builtin_amdgcn_mfma_f32_16x16x32_bf16(        \
            av2_[ii], bg_[nn], accg[4 + ii][nn], 0, 0, 0);                 \
        accu[4 + ii][nn] = __builtin_amdgcn_mfma_f32_16x16x32_bf16(        \
            av2_[ii], bu_[nn], accu[4 + ii][nn], 0, 0, 0);                 \
      }                                                                    \
    __builtin_amdgcn_s_setprio(0);                                         \
    BAR;                                                                   \
  } while (0)

  // prologue: stage regions for phases 0,1,2; confirm 0,1; prefetch ph0.
  SAF(0, 0, 0); SGU(0, 0, 0); SAF(0, 1, 0); SGU(0, 1, 0);
  SAF(1, 0, 1); SGU(1, 0, 1);
  VM4;
  BAR;
  PFF(avA, av2A, bgA, buA, 0, 0);

  constexpr int NI = ntiles >> 1;  // 32
  for (int it = 0; it < NI; ++it) {
    const int t0 = it * 2;
    PHF(avA, av2A, bgA, buA, avB, av2B, bgB, buB,
        { SAF(t0 + 1, 1, 1); SGU(t0 + 1, 1, 1); }, (void)0, 0, 1);
    PHF(avB, av2B, bgB, buB, avA, av2A, bgA, buA,
        { SAF(t0 + 2, 0, 0); SGU(t0 + 2, 0, 0); }, VM4, 1, 0);
    PHF(avA, av2A, bgA, buA, avB, av2B, bgB, buB,
        { SAF(t0 + 2, 1, 0); SGU(t0 + 2, 1, 0); }, (void)0, 1, 1);
    PHF(avB, av2B, bgB, buB, avA, av2A, bgA, buA,
        { SAF(t0 + 3, 0, 1); SGU(t0 + 3, 0, 1); }, VM4, 0, 0);
  }
  asm volatile("s_waitcnt vmcnt(0)" ::: "memory");

  // epilogue: h = silu(g) * u
  const int rb0 = m0 + wr * 128 + quad * 4;
  const int cb0 = n0 + wc * 32 + r16;
#pragma unroll
  for (int mf = 0; mf < 8; ++mf) {
#pragma unroll
    for (int nf = 0; nf < 2; ++nf) {
      f32x4 vg = accg[mf][nf];
      f32x4 vu = accu[mf][nf];
      int row = rb0 + mf * 16;
      int col = cb0 + nf * 16;
#pragma unroll
      for (int j = 0; j < 4; ++j) {
        float g = vg[j];
        float sv = g / (1.f + __expf(-g));
        H[(size_t)(row + j) * DFF + col] = f2bf(sv * vu[j]);
      }
    }
  }
#undef SAF
#undef SGU
#undef PFF
#undef PHF
}

// ======== down GEMM: out[M, DMODEL] = h @ WdT^T, f32 out ========
// Same top-of-cluster unpinned prefetch; n-major dispatch.
__global__ __launch_bounds__(512, 2) void k_down(
    const u16* __restrict__ A, const u16* __restrict__ BT,
    float* __restrict__ C) {
  constexpr int Ndim = DMODEL, Kdim = DFF;
  __shared__ u16 As[2][2][256 * 32];
  __shared__ u16 Bs[2][2][256 * 32];

  const int nidx = blockIdx.x & 15;   // n-major
  const int midx = blockIdx.x >> 4;
  const int m0 = midx << 8;
  const int n0 = nidx << 8;
  const int t = threadIdx.x;
  const int lane = t & 63;
  const int wid = t >> 6;
  const int wr = wid >> 2, wc = wid & 3;
  const int r16 = lane & 15, quad = lane >> 4;

  const int lrow4 = lane >> 2;
  const int sslot = ((lane & 3) ^ ((lane >> 3) & 3)) << 3;
  const u16* Asrc = A + (size_t)(m0 + wid * 16 + lrow4) * Kdim + sslot;
  const u16* Bsrc = BT + (size_t)(n0 + wid * 16 + lrow4) * Kdim + sslot;
  const size_t rstep = (size_t)128 * Kdim;
  const int lbo = wid * 512;
  constexpr int ntiles = Kdim >> 6;  // 172

#define SA(tt, kh, bf) do {                                                \
    int ttw = (tt) < ntiles ? (tt) : (tt) - ntiles;                        \
    size_t ko = ((size_t)ttw << 6) + ((kh) << 5);                          \
    GLD16(Asrc + ko,         &As[bf][kh][lbo]);                            \
    GLD16(Asrc + ko + rstep, &As[bf][kh][lbo + 4096]);                     \
  } while (0)
#define SB(tt, kh, bf) do {                                                \
    int ttw = (tt) < ntiles ? (tt) : (tt) - ntiles;                        \
    size_t ko = ((size_t)ttw << 6) + ((kh) << 5);                          \
    GLD16(Bsrc + ko,         &Bs[bf][kh][lbo]);                            \
    GLD16(Bsrc + ko + rstep, &Bs[bf][kh][lbo + 4096]);                     \
  } while (0)

  const int fragoff = (quad ^ ((r16 >> 1) & 3)) << 3;
  const int abase = (wr * 128 + r16) * 32 + fragoff;
  const int bbase = (wc * 64 + r16) * 32 + fragoff;

  f32x4 acc[8][4];
  const f32x4 zf = {0.f, 0.f, 0.f, 0.f};
#pragma unroll
  for (int mf = 0; mf < 8; ++mf)
#pragma unroll
    for (int nf = 0; nf < 4; ++nf) acc[mf][nf] = zf;

  bf16x8 avA[4], av2A[4], bvA[4];
  bf16x8 avB[4], av2B[4], bvB[4];

#define PFD(av_, av2_, bv_, bf, kk) do {                                   \
    _Pragma("unroll") for (int ii = 0; ii < 4; ++ii) {                     \
      av_[ii] = *reinterpret_cast<const bf16x8*>(                          \
          &As[bf][kk][abase + ii * 512]);                                  \
      av2_[ii] = *reinterpret_cast<const bf16x8*>(                         \
          &As[bf][kk][abase + 2048 + ii * 512]);                           \
    }                                                                      \
    _Pragma("unroll") for (int nn = 0; nn < 4; ++nn)                       \
      bv_[nn] = *reinterpret_cast<const bf16x8*>(                          \
          &Bs[bf][kk][bbase + nn * 512]);                                  \
  } while (0)

#define PHD(av_, av2_, bv_, nav_, nav2_, nbv_, STG_, VMW, bfn, kkn) do {   \
    STG_;                                                                  \
    VMW;                                                                   \
    BAR;                                                                   \
    PFD(nav_, nav2_, nbv_, bfn, kkn);                                      \
    __builtin_amdgcn_s_setprio(1);                                         \
    _Pragma("unroll") for (int ii = 0; ii < 4; ++ii)                       \
      _Pragma("unroll") for (int nn = 0; nn < 4; ++nn)                     \
        acc[ii][nn] = __builtin_amdgcn_mfma_f32_16x16x32_bf16(             \
            av_[ii], bv_[nn], acc[ii][nn], 0, 0, 0);                       \
    _Pragma("unroll") for (int ii = 0; ii < 4; ++ii)                       \
      _Pragma("unroll") for (int nn = 0; nn < 4; ++nn)                     \
        acc[4 + ii][nn] = __builtin_amdgcn_mfma_f32_16x16x32_bf16(         \
            av2_[ii], bv_[nn], acc[4 + ii][nn], 0, 0, 0);                  \
    __builtin_amdgcn_s_setprio(0);                                         \
    BAR;                                                                   \
  } while (0)

  SA(0, 0, 0); SB(0, 0, 0); SA(0, 1, 0); SB(0, 1, 0); SA(1, 0, 1); SB(1, 0, 1);
  VM4;
  BAR;
  PFD(avA, av2A, bvA, 0, 0);

  constexpr int NI = ntiles >> 1;  // 86
  for (int it = 0; it < NI; ++it) {
    const int t0 = it * 2;
    PHD(avA, av2A, bvA, avB, av2B, bvB,
        { SA(t0 + 1, 1, 1); SB(t0 + 1, 1, 1); }, (void)0, 0, 1);
    PHD(avB, av2B, bvB, avA, av2A, bvA,
        { SA(t0 + 2, 0, 0); SB(t0 + 2, 0, 0); }, VM4, 1, 0);
    PHD(avA, av2A, bvA, avB, av2B, bvB,
        { SA(t0 + 2, 1, 0); SB(t0 + 2, 1, 0); }, (void)0, 1, 1);
    PHD(avB, av2B, bvB, avA, av2A, bvA,
        { SA(t0 + 3, 0, 1); SB(t0 + 3, 0, 1); }, VM4, 0, 0);
  }
  asm volatile("s_waitcnt vmcnt(0)" ::: "memory");

  const int rb0 = m0 + wr * 128 + quad * 4;
  const int cb0 = n0 + wc * 64 + r16;
#pragma unroll
  for (int mf = 0; mf < 8; ++mf) {
#pragma unroll
    for (int nf = 0; nf < 4; ++nf) {
      f32x4 v = acc[mf][nf];
      int row = rb0 + mf * 16;
      int col = cb0 + nf * 16;
#pragma unroll
      for (int j = 0; j < 4; ++j)
        C[(size_t)(row + j) * Ndim + col] = v[j];
    }
  }
#undef SA
#undef SB
#undef PFD
#undef PHD
}

extern "C" void kernel_launch(void* const* d_in, const int* in_sizes, int n_in,
                              void* d_out, int out_size, void* d_ws, size_t ws_size,
                              hipStream_t stream) {
  const float* x  = (const float*)d_in[0];
  const int*   qg = (const int*)d_in[1];
  const int*   zg = (const int*)d_in[2];
  const float* sg = (const float*)d_in[3];
  const int*   qu = (const int*)d_in[4];
  const int*   zu = (const int*)d_in[5];
  const float* su = (const float*)d_in[6];
  const int*   qd = (const int*)d_in[7];
  const int*   zd = (const int*)d_in[8];
  const float* sd = (const float*)d_in[9];
  float* out = (float*)d_out;

  char* ws = (char*)d_ws;
  const size_t szXB = (size_t)MROWS * DMODEL * 2;
  const size_t szW  = (size_t)DMODEL * DFF * 2;
  u16* xb  = (u16*)(ws);
  u16* wgT = (u16*)(ws + szXB);
  u16* wuT = (u16*)(ws + szXB + szW);
  u16* wdT = (u16*)(ws + szXB + 2 * szW);
  u16* h   = (u16*)(ws + szXB + 3 * szW);  // [M][DFF] bf16

  k_cvt_x<<<(MROWS * DMODEL) / 1024, 256, 0, stream>>>(x, xb);
  k_dequant_T<<<dim3(DFF / 32, DMODEL / 32), 256, 0, stream>>>(qg, zg, sg, wgT, DMODEL, DFF);
  k_dequant_T<<<dim3(DFF / 32, DMODEL / 32), 256, 0, stream>>>(qu, zu, su, wuT, DMODEL, DFF);
  k_dequant_T<<<dim3(DMODEL / 32, DFF / 32), 256, 0, stream>>>(qd, zd, sd, wdT, DFF, DMODEL);

  // h = silu(x@Wg)*(x@Wu): grid 32m x 86n, m-major
  k_fused<<<(MROWS / 256) * (DFF / 128), 512, 0, stream>>>(xb, wgT, wuT, h);
  // out = h @ Wd: grid 32m x 16n, n-major
  k_down<<<(MROWS / 256) * (DMODEL / 256), 512, 0, stream>>>(h, wdT, out);
}

// Round 13
// 2051.372 us; speedup vs baseline: 1.2572x; 1.2572x over previous
//
#include <hip/hip_runtime.h>
#include <cstdint>

typedef unsigned short u16;
typedef unsigned int u32;
typedef unsigned char u8;
typedef signed char s8;
typedef __bf16 bf16_t;
typedef bf16_t bf16x8 __attribute__((ext_vector_type(8)));
typedef float f32x4 __attribute__((ext_vector_type(4)));
typedef int i32x4 __attribute__((ext_vector_type(4)));

#define DMODEL 4096
#define DFF 11008
#define MROWS 8192

__device__ __forceinline__ u16 f2bf(float f) {
  u32 u = __builtin_bit_cast(u32, f);
  u += 0x7FFFu + ((u >> 16) & 1u);   // RNE
  return (u16)(u >> 16);
}
__device__ __forceinline__ float bf2f(u16 h) {
  return __builtin_bit_cast(float, (u32)h << 16);
}

// async global->LDS, 16B per lane, wave-uniform LDS base + lane*16
#define GLD16(gptr, lptr)                                                  \
  __builtin_amdgcn_global_load_lds(                                        \
      (const __attribute__((address_space(1))) u32*)(gptr),                \
      (__attribute__((address_space(3))) u32*)(lptr), 16, 0, 0)

#define BAR asm volatile("s_barrier" ::: "memory")
#define VM4 asm volatile("s_waitcnt vmcnt(4)" ::: "memory")
#define LGKM0 asm volatile("s_waitcnt lgkmcnt(0)" ::: "memory")

// ---- x -> int8 with per-row scale: x8 = round(x/sx), sx = rowmax/127 ----
__global__ void k_quant_x(const float* __restrict__ x, s8* __restrict__ x8,
                          float* __restrict__ sx) {
  const int row = blockIdx.x;
  const int t = threadIdx.x;            // 256
  const int lane = t & 63, wid = t >> 6;
  const float4* xr = reinterpret_cast<const float4*>(x + (size_t)row * DMODEL);
  float4 v[4];
  float m = 0.f;
#pragma unroll
  for (int i = 0; i < 4; ++i) {
    v[i] = xr[t * 4 + i];
    m = fmaxf(m, fmaxf(fmaxf(fabsf(v[i].x), fabsf(v[i].y)),
                       fmaxf(fabsf(v[i].z), fabsf(v[i].w))));
  }
#pragma unroll
  for (int off = 32; off >= 1; off >>= 1) m = fmaxf(m, __shfl_xor(m, off));
  __shared__ float wm[4];
  if (lane == 0) wm[wid] = m;
  __syncthreads();
  float mall = fmaxf(fmaxf(wm[0], wm[1]), fmaxf(wm[2], wm[3]));
  mall = fmaxf(mall, 1e-8f);
  const float inv = 127.f / mall;
  if (t == 0) sx[row] = mall / 127.f;
  uint4 o;
  u32 p[4];
#pragma unroll
  for (int i = 0; i < 4; ++i) {
    int a = (int)rintf(v[i].x * inv), b = (int)rintf(v[i].y * inv);
    int c = (int)rintf(v[i].z * inv), d = (int)rintf(v[i].w * inv);
    p[i] = (u32)(a & 255) | ((u32)(b & 255) << 8) | ((u32)(c & 255) << 16) |
           ((u32)(d & 255) << 24);
  }
  o.x = p[0]; o.y = p[1]; o.z = p[2]; o.w = p[3];
  reinterpret_cast<uint4*>(x8 + (size_t)row * DMODEL)[t] = o;
}

// ---- dequant to INT8 (q - z), transposed w8[N][K] (scales applied in GEMM) --
__global__ void k_dequant_T8(const int* __restrict__ q, const int* __restrict__ z,
                             s8* __restrict__ w8, int K, int N) {
  __shared__ s8 tile[32][40];
  const int t = threadIdx.x;
  const int n0 = blockIdx.x << 5, k0 = blockIdx.y << 5;
  {
    const int kr = t >> 3, n4 = (t & 7) << 2;
    const int k = k0 + kr, g = k >> 7;
    const int4 qv = *reinterpret_cast<const int4*>(&q[(size_t)k * N + n0 + n4]);
    const int4 zv = *reinterpret_cast<const int4*>(&z[(size_t)g * N + n0 + n4]);
    tile[kr][n4 + 0] = (s8)(qv.x - zv.x);
    tile[kr][n4 + 1] = (s8)(qv.y - zv.y);
    tile[kr][n4 + 2] = (s8)(qv.z - zv.z);
    tile[kr][n4 + 3] = (s8)(qv.w - zv.w);
  }
  __syncthreads();
  {
    const int n = t >> 3, ks = (t & 7) << 2;
    uchar4 o;
    o.x = (u8)tile[ks + 0][n];
    o.y = (u8)tile[ks + 1][n];
    o.z = (u8)tile[ks + 2][n];
    o.w = (u8)tile[ks + 3][n];
    *reinterpret_cast<uchar4*>(&w8[(size_t)(n0 + n) * K + k0 + ks]) = o;
  }
}

// ---- dequant to bf16 (for the down projection), transposed wT[N][K] ----
__global__ void k_dequant_T(const int* __restrict__ q, const int* __restrict__ z,
                            const float* __restrict__ s, u16* __restrict__ wT,
                            int K, int N) {
  __shared__ u16 tile[32][36];
  const int t = threadIdx.x;
  const int n0 = blockIdx.x << 5, k0 = blockIdx.y << 5;
  {
    const int kr = t >> 3, n4 = (t & 7) << 2;
    const int k = k0 + kr, g = k >> 7;
    const int4 qv = *reinterpret_cast<const int4*>(&q[(size_t)k * N + n0 + n4]);
    const int4 zv = *reinterpret_cast<const int4*>(&z[(size_t)g * N + n0 + n4]);
    const float4 sv = *reinterpret_cast<const float4*>(&s[(size_t)g * N + n0 + n4]);
    ushort4 o;
    o.x = f2bf((float)(qv.x - zv.x) * sv.x);
    o.y = f2bf((float)(qv.y - zv.y) * sv.y);
    o.z = f2bf((float)(qv.z - zv.z) * sv.z);
    o.w = f2bf((float)(qv.w - zv.w) * sv.w);
    *reinterpret_cast<ushort4*>(&tile[kr][n4]) = o;
  }
  __syncthreads();
  {
    const int n = t >> 3, ks = (t & 7) << 2;
    ushort4 o;
    o.x = tile[ks + 0][n];
    o.y = tile[ks + 1][n];
    o.z = tile[ks + 2][n];
    o.w = tile[ks + 3][n];
    *reinterpret_cast<ushort4*>(&wT[(size_t)(n0 + n) * K + k0 + ks]) = o;
  }
}

// ======== fused gate+up, INT8 MFMA: h = silu(x@Wg)*(x@Wu), bf16 out ========
// R10 structure (best measured total). CHANGE: per-group column scales
// staged once into LDS in the prologue (32KB) — removes the 4 per-phase
// global scale loads from the VM4 critical path. Scale region = 32 groups
// x 128 cols x 2 ops = 1024 float4 per op (k<2 loop — R12's k<4 was an
// OOB bug: g ran to 63 vs 32 groups, overflowing sg reads and scl LDS).
__global__ __launch_bounds__(512, 2) void k_fused_i8(
    const s8* __restrict__ A, const s8* __restrict__ Bg,
    const s8* __restrict__ Bu, const float* __restrict__ sx,
    const float* __restrict__ sg, const float* __restrict__ su,
    u16* __restrict__ H) {
  constexpr int Kdim = DMODEL;
  constexpr int ntiles = Kdim >> 6;  // 64
  __shared__ s8 Ab[3][256 * 64];   // 48KB
  __shared__ s8 Bgb[3][128 * 64];  // 24KB
  __shared__ s8 Bub[3][128 * 64];  // 24KB
  __shared__ float scl[2][32 * 128];  // 32KB: [op][group][col]  (total 128KB)

  const int midx = blockIdx.x & 31, nidx = blockIdx.x >> 5;
  const int m0 = midx << 8, n0 = nidx << 7;
  const int t = threadIdx.x;
  const int lane = t & 63;
  const int wid = t >> 6;
  const int wr = wid >> 2, wc = wid & 3;
  const int r16 = lane & 15, quad = lane >> 4;

  // staging: lane l -> row base + l/4, slot l&3 (16B units); source slot
  // pre-swizzled: slot ^ ((lrow>>1)&3)
  const int lrow = lane >> 2;
  const int sswz = ((lane & 3) ^ ((lrow >> 1) & 3)) << 4;  // byte offset
  const s8* Asrc = A + (size_t)(m0 + wid * 16 + lrow) * Kdim + sswz;
  const s8* Gsrc = Bg + (size_t)(n0 + wid * 16 + lrow) * Kdim + sswz;
  const s8* Usrc = Bu + (size_t)(n0 + wid * 16 + lrow) * Kdim + sswz;
  const size_t rstepA = (size_t)128 * Kdim;
  const int ldst = wid * 1024;  // byte offset of wave chunk

#define STG(tt, bs) do {                                                   \
    size_t ko = (size_t)((tt) & (ntiles - 1)) << 6;                        \
    GLD16(Asrc + ko,          &Ab[bs][ldst]);                              \
    GLD16(Asrc + ko + rstepA, &Ab[bs][ldst + 8192]);                       \
    GLD16(Gsrc + ko,          &Bgb[bs][ldst]);                             \
    GLD16(Usrc + ko,          &Bub[bs][ldst]);                             \
  } while (0)

  // fragment reads: A row = wr*128 + mf*16 + r16, 16B at swizzled slot quad
  const int aswz = (quad ^ ((r16 >> 1) & 3)) << 4;
  const int abase = (wr * 128 + r16) * 64 + aswz;  // + mf*1024
  const int bbase = (wc * 32 + r16) * 64 + aswz;   // + nf*1024

  f32x4 facg[8][2], facu[8][2];
  const f32x4 zf = {0.f, 0.f, 0.f, 0.f};
#pragma unroll
  for (int mf = 0; mf < 8; ++mf)
#pragma unroll
    for (int nf = 0; nf < 2; ++nf) { facg[mf][nf] = zf; facu[mf][nf] = zf; }
  const i32x4 zi = {0, 0, 0, 0};

  // ---- prologue: stage scales into LDS (once), then tiles 0,1 ----
  // 32 groups x 128 cols per op = 1024 float4 per op; 512 thr x 2 iters.
#pragma unroll
  for (int k = 0; k < 2; ++k) {
    int j = t + k * 512;          // float4 index 0..1023
    int g = j >> 5;               // 32 float4 per group-row -> g in [0,32)
    int c = (j & 31) << 2;        // col in [0,128), step 4
    *reinterpret_cast<float4*>(&scl[0][g * 128 + c]) =
        *reinterpret_cast<const float4*>(&sg[(size_t)g * DFF + n0 + c]);
    *reinterpret_cast<float4*>(&scl[1][g * 128 + c]) =
        *reinterpret_cast<const float4*>(&su[(size_t)g * DFF + n0 + c]);
  }
  STG(0, 0); STG(1, 1);
  VM4;
  LGKM0;  // scl ds_writes visible to all waves after the barrier
  BAR;

  const int sloc = wc * 32 + r16;  // column within block (+16 for nf=1)

  int cur = 0, nb = 2;
  for (int p = 0; p < ntiles; ++p) {
    // fragment ds_reads for this tile
    i32x4 av[8], bgv[2], buv[2];
#pragma unroll
    for (int mf = 0; mf < 8; ++mf)
      av[mf] = *reinterpret_cast<const i32x4*>(&Ab[cur][abase + mf * 1024]);
#pragma unroll
    for (int nf = 0; nf < 2; ++nf) {
      bgv[nf] = *reinterpret_cast<const i32x4*>(&Bgb[cur][bbase + nf * 1024]);
      buv[nf] = *reinterpret_cast<const i32x4*>(&Bub[cur][bbase + nf * 1024]);
    }
    // group scales from LDS (broadcast-pattern ds_read_b32, off VMEM path)
    const int g = p >> 1;
    float s_g0 = scl[0][g * 128 + sloc];
    float s_g1 = scl[0][g * 128 + sloc + 16];
    float s_u0 = scl[1][g * 128 + sloc];
    float s_u1 = scl[1][g * 128 + sloc + 16];
    STG(p + 2, nb);
    VM4;  // confirms stage(p+1); leaves stage(p+2) in flight
    __builtin_amdgcn_s_setprio(1);
#pragma unroll
    for (int mf = 0; mf < 8; ++mf) {
      i32x4 ig0 = __builtin_amdgcn_mfma_i32_16x16x64_i8(av[mf], bgv[0], zi, 0, 0, 0);
      i32x4 ig1 = __builtin_amdgcn_mfma_i32_16x16x64_i8(av[mf], bgv[1], zi, 0, 0, 0);
      i32x4 iu0 = __builtin_amdgcn_mfma_i32_16x16x64_i8(av[mf], buv[0], zi, 0, 0, 0);
      i32x4 iu1 = __builtin_amdgcn_mfma_i32_16x16x64_i8(av[mf], buv[1], zi, 0, 0, 0);
#pragma unroll
      for (int j = 0; j < 4; ++j) {
        facg[mf][0][j] += (float)ig0[j] * s_g0;
        facg[mf][1][j] += (float)ig1[j] * s_g1;
        facu[mf][0][j] += (float)iu0[j] * s_u0;
        facu[mf][1][j] += (float)iu1[j] * s_u1;
      }
    }
    __builtin_amdgcn_s_setprio(0);
    BAR;
    cur = (cur == 2) ? 0 : cur + 1;
    nb = (nb == 2) ? 0 : nb + 1;
  }
  asm volatile("s_waitcnt vmcnt(0)" ::: "memory");

  // epilogue: apply per-row x-scale, silu(g)*u -> bf16
  const int rb0 = m0 + wr * 128 + quad * 4;
  const int cb0 = n0 + wc * 32 + r16;
#pragma unroll
  for (int mf = 0; mf < 8; ++mf) {
#pragma unroll
    for (int j = 0; j < 4; ++j) {
      const int row = rb0 + mf * 16 + j;
      const float sxr = sx[row];
#pragma unroll
      for (int nf = 0; nf < 2; ++nf) {
        float gv = facg[mf][nf][j] * sxr;
        float uv = facu[mf][nf][j] * sxr;
        float sv = gv / (1.f + __expf(-gv));
        H[(size_t)row * DFF + cb0 + nf * 16] = f2bf(sv * uv);
      }
    }
  }
#undef STG
}

// ======== down GEMM (bf16, R6/R9-proven): out = h @ WdT^T, f32 out ========
__global__ __launch_bounds__(512, 2) void k_down(
    const u16* __restrict__ A, const u16* __restrict__ BT,
    float* __restrict__ C) {
  constexpr int Ndim = DMODEL, Kdim = DFF;
  __shared__ u16 As[2][2][256 * 32];
  __shared__ u16 Bs[2][2][256 * 32];

  const int nidx = blockIdx.x & 15;   // n-major
  const int midx = blockIdx.x >> 4;
  const int m0 = midx << 8;
  const int n0 = nidx << 8;
  const int t = threadIdx.x;
  const int lane = t & 63;
  const int wid = t >> 6;
  const int wr = wid >> 2, wc = wid & 3;
  const int r16 = lane & 15, quad = lane >> 4;

  const int lrow4 = lane >> 2;
  const int sslot = ((lane & 3) ^ ((lane >> 3) & 3)) << 3;
  const u16* Asrc = A + (size_t)(m0 + wid * 16 + lrow4) * Kdim + sslot;
  const u16* Bsrc = BT + (size_t)(n0 + wid * 16 + lrow4) * Kdim + sslot;
  const size_t rstep = (size_t)128 * Kdim;
  const int lbo = wid * 512;
  constexpr int ntiles = Kdim >> 6;  // 172

#define SA(tt, kh, bf) do {                                                \
    int ttw = (tt) < ntiles ? (tt) : (tt) - ntiles;                        \
    size_t ko = ((size_t)ttw << 6) + ((kh) << 5);                          \
    GLD16(Asrc + ko,         &As[bf][kh][lbo]);                            \
    GLD16(Asrc + ko + rstep, &As[bf][kh][lbo + 4096]);                     \
  } while (0)
#define SB(tt, kh, bf) do {                                                \
    int ttw = (tt) < ntiles ? (tt) : (tt) - ntiles;                        \
    size_t ko = ((size_t)ttw << 6) + ((kh) << 5);                          \
    GLD16(Bsrc + ko,         &Bs[bf][kh][lbo]);                            \
    GLD16(Bsrc + ko + rstep, &Bs[bf][kh][lbo + 4096]);                     \
  } while (0)

  const int fragoff = (quad ^ ((r16 >> 1) & 3)) << 3;
  const int abase = (wr * 128 + r16) * 32 + fragoff;
  const int bbase = (wc * 64 + r16) * 32 + fragoff;

  f32x4 acc[8][4];
  const f32x4 zf = {0.f, 0.f, 0.f, 0.f};
#pragma unroll
  for (int mf = 0; mf < 8; ++mf)
#pragma unroll
    for (int nf = 0; nf < 4; ++nf) acc[mf][nf] = zf;

  bf16x8 avA[4], av2A[4], bvA[4];
  bf16x8 avB[4], av2B[4], bvB[4];

#define PFD(av_, av2_, bv_, bf, kk) do {                                   \
    _Pragma("unroll") for (int ii = 0; ii < 4; ++ii) {                     \
      av_[ii] = *reinterpret_cast<const bf16x8*>(                          \
          &As[bf][kk][abase + ii * 512]);                                  \
      av2_[ii] = *reinterpret_cast<const bf16x8*>(                         \
          &As[bf][kk][abase + 2048 + ii * 512]);                           \
    }                                                                      \
    _Pragma("unroll") for (int nn = 0; nn < 4; ++nn)                       \
      bv_[nn] = *reinterpret_cast<const bf16x8*>(                          \
          &Bs[bf][kk][bbase + nn * 512]);                                  \
  } while (0)

#define PHD(av_, av2_, bv_, nav_, nav2_, nbv_, STG_, VMW, bfn, kkn) do {   \
    STG_;                                                                  \
    VMW;                                                                   \
    BAR;                                                                   \
    __builtin_amdgcn_s_setprio(1);                                         \
    _Pragma("unroll") for (int ii = 0; ii < 4; ++ii)                       \
      _Pragma("unroll") for (int nn = 0; nn < 4; ++nn)                     \
        acc[ii][nn] = __builtin_amdgcn_mfma_f32_16x16x32_bf16(             \
            av_[ii], bv_[nn], acc[ii][nn], 0, 0, 0);                       \
    PFD(nav_, nav2_, nbv_, bfn, kkn);                                      \
    _Pragma("unroll") for (int ii = 0; ii < 4; ++ii)                       \
      _Pragma("unroll") for (int nn = 0; nn < 4; ++nn)                     \
        acc[4 + ii][nn] = __builtin_amdgcn_mfma_f32_16x16x32_bf16(         \
            av2_[ii], bv_[nn], acc[4 + ii][nn], 0, 0, 0);                  \
    __builtin_amdgcn_s_setprio(0);                                         \
    BAR;                                                                   \
  } while (0)

  SA(0, 0, 0); SB(0, 0, 0); SA(0, 1, 0); SB(0, 1, 0); SA(1, 0, 1); SB(1, 0, 1);
  VM4;
  BAR;
  PFD(avA, av2A, bvA, 0, 0);

  constexpr int NI = ntiles >> 1;  // 86
  for (int it = 0; it < NI; ++it) {
    const int t0 = it * 2;
    PHD(avA, av2A, bvA, avB, av2B, bvB,
        { SA(t0 + 1, 1, 1); SB(t0 + 1, 1, 1); }, (void)0, 0, 1);
    PHD(avB, av2B, bvB, avA, av2A, bvA,
        { SA(t0 + 2, 0, 0); SB(t0 + 2, 0, 0); }, VM4, 1, 0);
    PHD(avA, av2A, bvA, avB, av2B, bvB,
        { SA(t0 + 2, 1, 0); SB(t0 + 2, 1, 0); }, (void)0, 1, 1);
    PHD(avB, av2B, bvB, avA, av2A, bvA,
        { SA(t0 + 3, 0, 1); SB(t0 + 3, 0, 1); }, VM4, 0, 0);
  }
  asm volatile("s_waitcnt vmcnt(0)" ::: "memory");

  const int rb0 = m0 + wr * 128 + quad * 4;
  const int cb0 = n0 + wc * 64 + r16;
#pragma unroll
  for (int mf = 0; mf < 8; ++mf) {
#pragma unroll
    for (int nf = 0; nf < 4; ++nf) {
      f32x4 v = acc[mf][nf];
      int row = rb0 + mf * 16;
      int col = cb0 + nf * 16;
#pragma unroll
      for (int j = 0; j < 4; ++j)
        C[(size_t)(row + j) * Ndim + col] = v[j];
    }
  }
#undef SA
#undef SB
#undef PFD
#undef PHD
}

extern "C" void kernel_launch(void* const* d_in, const int* in_sizes, int n_in,
                              void* d_out, int out_size, void* d_ws, size_t ws_size,
                              hipStream_t stream) {
  const float* x  = (const float*)d_in[0];
  const int*   qg = (const int*)d_in[1];
  const int*   zg = (const int*)d_in[2];
  const float* sg = (const float*)d_in[3];
  const int*   qu = (const int*)d_in[4];
  const int*   zu = (const int*)d_in[5];
  const float* su = (const float*)d_in[6];
  const int*   qd = (const int*)d_in[7];
  const int*   zd = (const int*)d_in[8];
  const float* sd = (const float*)d_in[9];
  float* out = (float*)d_out;

  char* ws = (char*)d_ws;
  const size_t szX8 = (size_t)MROWS * DMODEL;        // 33.5 MB
  const size_t szSX = (size_t)MROWS * 4;             // 32 KB
  const size_t szW8 = (size_t)DMODEL * DFF;          // 45 MB
  const size_t szWD = (size_t)DFF * DMODEL * 2;      // 90 MB
  s8*    x8  = (s8*)(ws);
  float* sx  = (float*)(ws + szX8);
  s8*    wg8 = (s8*)(ws + szX8 + szSX);
  s8*    wu8 = (s8*)(ws + szX8 + szSX + szW8);
  u16*   wdT = (u16*)(ws + szX8 + szSX + 2 * szW8);
  u16*   h   = (u16*)(ws + szX8 + szSX + 2 * szW8 + szWD);  // [M][DFF] bf16

  k_quant_x<<<MROWS, 256, 0, stream>>>(x, x8, sx);
  k_dequant_T8<<<dim3(DFF / 32, DMODEL / 32), 256, 0, stream>>>(qg, zg, wg8, DMODEL, DFF);
  k_dequant_T8<<<dim3(DFF / 32, DMODEL / 32), 256, 0, stream>>>(qu, zu, wu8, DMODEL, DFF);
  k_dequant_T<<<dim3(DMODEL / 32, DFF / 32), 256, 0, stream>>>(qd, zd, sd, wdT, DFF, DMODEL);

  // h = silu(x@Wg)*(x@Wu): int8 MFMA, grid 32m x 86n (m-major)
  k_fused_i8<<<(MROWS / 256) * (DFF / 128), 512, 0, stream>>>(
      x8, wg8, wu8, sx, sg, su, h);
  // out = h @ Wd: bf16 MFMA, grid 32m x 16n (n-major)
  k_down<<<(MROWS / 256) * (DMODEL / 256), 512, 0, stream>>>(h, wdT, out);
}